// Round 3
// baseline (141.490 us; speedup 1.0000x reference)
//
#include <hip/hip_runtime.h>

#define NN 8192
#define BB 32
#define EMB 16
#define HID 64
#define MS 16          // m-range splits (per-split partial buffers, no atomics)
#define TNB 256        // n per block (64 per wave)
#define TM 64          // m per tile
#define VT_PITCH 8192  // bf16 elems per VT row

typedef __attribute__((ext_vector_type(8))) short bf16x8;
typedef __attribute__((ext_vector_type(4))) float f32x4;

static __device__ inline short f2b(float f) {           // round-to-nearest-even
    union { float f; unsigned u; } v; v.f = f;
    unsigned r = (v.u + 0x7fffu + ((v.u >> 16) & 1u)) >> 16;
    return (short)r;
}

// ---------------------------------------------------------------------------
// K1: VT[j][m] = bf16(x[b=j>>1][m][c=j&1]);  adjB = bf16(adj); adjS = bf16(adj*log2e)
// ---------------------------------------------------------------------------
__global__ void k_build(const float* __restrict__ x, const float* __restrict__ adj,
                        short* __restrict__ VT, short* __restrict__ adjB,
                        short* __restrict__ adjS) {
    int t = threadIdx.x;
    if (blockIdx.x < 512) {
        int idx = blockIdx.x * 256 + t;          // 0 .. 131071
        int b = idx >> 12;
        int m = (idx & 4095) * 2;
        float4 xx = *(const float4*)(x + (size_t)b * NN * 2 + 2 * m);
        unsigned u0 = (unsigned short)f2b(xx.x) | ((unsigned)(unsigned short)f2b(xx.z) << 16);
        unsigned u1 = (unsigned short)f2b(xx.y) | ((unsigned)(unsigned short)f2b(xx.w) << 16);
        *(unsigned*)(VT + (size_t)(2 * b) * VT_PITCH + m) = u0;
        *(unsigned*)(VT + (size_t)(2 * b + 1) * VT_PITCH + m) = u1;
    } else {
        const float L2E = 1.4426950408889634f;
        int idx = (blockIdx.x - 512) * 256 + t;   // 0 .. 32767
        float4 aa = *(const float4*)(adj + (size_t)idx * 4);
        uint2 ub, us;
        ub.x = (unsigned short)f2b(aa.x) | ((unsigned)(unsigned short)f2b(aa.y) << 16);
        ub.y = (unsigned short)f2b(aa.z) | ((unsigned)(unsigned short)f2b(aa.w) << 16);
        us.x = (unsigned short)f2b(aa.x * L2E) | ((unsigned)(unsigned short)f2b(aa.y * L2E) << 16);
        us.y = (unsigned short)f2b(aa.z * L2E) | ((unsigned)(unsigned short)f2b(aa.w * L2E) << 16);
        *(uint2*)(adjB + (size_t)idx * 4) = ub;
        *(uint2*)(adjS + (size_t)idx * 4) = us;
    }
}

// ---------------------------------------------------------------------------
// K2: node-adaptive weights: Wbuf[n][c*64+o], c = {x0,x1,y0,y1,bias}
// ---------------------------------------------------------------------------
__global__ void k_weights(const float* __restrict__ adj, const float* __restrict__ wp,
                          const float* __restrict__ bp, float* __restrict__ Wbuf) {
    const int nl = threadIdx.x >> 4, og = threadIdx.x & 15;
    const int n = blockIdx.x * 16 + nl;
    const float4* wp4 = (const float4*)wp;
    const float4* bp4 = (const float4*)bp;
    float an[EMB];
#pragma unroll
    for (int d = 0; d < EMB; ++d) an[d] = adj[n * EMB + d];
    float4 w[5];
#pragma unroll
    for (int c = 0; c < 5; ++c) { w[c].x = w[c].y = w[c].z = w[c].w = 0.f; }
#pragma unroll
    for (int d = 0; d < EMB; ++d) {
        float a = an[d];
#pragma unroll
        for (int c = 0; c < 4; ++c) {
            float4 p = wp4[(d * 4 + c) * 16 + og];
            w[c].x += a * p.x; w[c].y += a * p.y; w[c].z += a * p.z; w[c].w += a * p.w;
        }
        float4 pb = bp4[d * 16 + og];
        w[4].x += a * pb.x; w[4].y += a * pb.y; w[4].z += a * pb.z; w[4].w += a * pb.w;
    }
#pragma unroll
    for (int c = 0; c < 5; ++c)
        *(float4*)(Wbuf + (size_t)n * 320 + c * 64 + og * 4) = w[c];
}

// ---------------------------------------------------------------------------
// K3: barrier-free MFMA flash propagation, fragments loaded direct from global.
// Block = 256 thr (4 independent waves x 64 n). Partial ynum/den per split.
// ---------------------------------------------------------------------------
__launch_bounds__(256, 2)
__global__ void k_prop(const short* __restrict__ adjB, const short* __restrict__ adjS,
                       const short* __restrict__ VT,
                       float* __restrict__ ynum, float* __restrict__ den) {
    const int t = threadIdx.x;
    const int wv = t >> 6;
    const int lane = t & 63;
    const int l = lane & 15;
    const int q = lane >> 4;
    const int n0 = blockIdx.x * TNB + wv * 64;
    const int mbeg = blockIdx.y * (NN / MS);

    // score B-fragments: 4 x 16 n-rows, k>=16 zeroed (scaled side)
    bf16x8 Bn[4];
    bf16x8 zv = {0, 0, 0, 0, 0, 0, 0, 0};
#pragma unroll
    for (int s = 0; s < 4; ++s) {
        const short* src = adjS + (size_t)(n0 + 16 * s + l) * EMB + (q & 1) * 8;
        bf16x8 v = *(const bf16x8*)src;
        Bn[s] = (q < 2) ? v : zv;
    }
    const short one = (short)0x3F80;
    bf16x8 ones = {one, one, one, one, one, one, one, one};

    f32x4 acc[4][4];   // [u][s] : O^T rows 16u+4q+r, cols n0+16s+l
    f32x4 dacc[4];
#pragma unroll
    for (int u = 0; u < 4; ++u)
#pragma unroll
        for (int s = 0; s < 4; ++s) { acc[u][s][0] = acc[u][s][1] = acc[u][s][2] = acc[u][s][3] = 0.f; }
#pragma unroll
    for (int s = 0; s < 4; ++s) { dacc[s][0] = dacc[s][1] = dacc[s][2] = dacc[s][3] = 0.f; }

    const int mrow_b = 8 * (l >> 2) + (l & 3);   // permuted A-row base

    for (int m0 = mbeg; m0 < mbeg + (NN / MS); m0 += TM) {
        // issue all 12 fragment loads for this tile
        bf16x8 Af[2][2], Vf[2][4];
#pragma unroll
        for (int c = 0; c < 2; ++c)
#pragma unroll
            for (int h = 0; h < 2; ++h)
                Af[c][h] = *(const bf16x8*)(adjB + (size_t)(m0 + 32 * c + mrow_b + 4 * h) * EMB + (q & 1) * 8);
#pragma unroll
        for (int c = 0; c < 2; ++c)
#pragma unroll
            for (int u = 0; u < 4; ++u)
                Vf[c][u] = *(const bf16x8*)(VT + (size_t)(16 * u + l) * VT_PITCH + m0 + 32 * c + q * 8);

#pragma unroll
        for (int c = 0; c < 2; ++c) {
            f32x4 z = {0.f, 0.f, 0.f, 0.f};
            f32x4 S0[4], S1[4];
#pragma unroll
            for (int s = 0; s < 4; ++s) {
                S0[s] = __builtin_amdgcn_mfma_f32_16x16x32_bf16(Af[c][0], Bn[s], z, 0, 0, 0);
                S1[s] = __builtin_amdgcn_mfma_f32_16x16x32_bf16(Af[c][1], Bn[s], z, 0, 0, 0);
            }
#pragma unroll
            for (int s = 0; s < 4; ++s) {
                // w[j] for j=4h+r : exp2(max(S,0)) (n-side pre-scaled by log2e)
                unsigned wb[8];
#pragma unroll
                for (int r = 0; r < 4; ++r) {
                    union { float f; unsigned u; } p0, p1;
                    p0.f = __builtin_amdgcn_exp2f(fmaxf(S0[s][r], 0.f));
                    p1.f = __builtin_amdgcn_exp2f(fmaxf(S1[s][r], 0.f));
                    wb[r] = p0.u;        // h=0 -> j=r
                    wb[4 + r] = p1.u;    // h=1 -> j=4+r
                }
                union { bf16x8 v; unsigned d[4]; } pf;
#pragma unroll
                for (int dd = 0; dd < 4; ++dd)
                    pf.d[dd] = (wb[2 * dd + 1] & 0xFFFF0000u) | (wb[2 * dd] >> 16);  // trunc pack
#pragma unroll
                for (int u = 0; u < 4; ++u)
                    acc[u][s] = __builtin_amdgcn_mfma_f32_16x16x32_bf16(Vf[c][u], pf.v, acc[u][s], 0, 0, 0);
                dacc[s] = __builtin_amdgcn_mfma_f32_16x16x32_bf16(ones, pf.v, dacc[s], 0, 0, 0);
            }
        }
    }

    // stores: ynum partial [split][n][64], 64B-contiguous per 4 lanes
    float* yp = ynum + (size_t)blockIdx.y * NN * HID;
#pragma unroll
    for (int s = 0; s < 4; ++s) {
#pragma unroll
        for (int u = 0; u < 4; ++u)
            *(f32x4*)(yp + (size_t)(n0 + 16 * s + l) * HID + 16 * u + 4 * q) = acc[u][s];
        if (q == 0) den[(size_t)blockIdx.y * NN + n0 + 16 * s + l] = dacc[s][0];
    }
}

// ---------------------------------------------------------------------------
// K4: epilogue. Block = 256 thr, 16 nodes; reduce MS partials, normalize,
// apply per-node weights, write out [32][8192][64].
// ---------------------------------------------------------------------------
__global__ void k_epi(const float* __restrict__ Wbuf, const float* __restrict__ x,
                      const float* __restrict__ ynum, const float* __restrict__ den,
                      float* __restrict__ out) {
    const int nl = threadIdx.x >> 4, og = threadIdx.x & 15;
    const int n = blockIdx.x * 16 + nl;
    __shared__ float xl[16][68];
    __shared__ float yl[16][68];

    float4 W[5];
#pragma unroll
    for (int c = 0; c < 5; ++c)
        W[c] = *(const float4*)(Wbuf + (size_t)n * 320 + c * 64 + og * 4);

    float4 ysum; ysum.x = ysum.y = ysum.z = ysum.w = 0.f;
    float dsum = 0.f;
#pragma unroll
    for (int s = 0; s < MS; ++s) {
        float4 p = *(const float4*)(ynum + ((size_t)s * NN + n) * HID + og * 4);
        ysum.x += p.x; ysum.y += p.y; ysum.z += p.z; ysum.w += p.w;
        dsum += den[(size_t)s * NN + n];
    }
    float rden = 1.f / dsum;
    *(float4*)&yl[nl][og * 4] = make_float4(ysum.x * rden, ysum.y * rden, ysum.z * rden, ysum.w * rden);

    float2 x0 = *(const float2*)(x + ((size_t)(og * 2) * NN + n) * 2);
    float2 x1 = *(const float2*)(x + ((size_t)(og * 2 + 1) * NN + n) * 2);
    xl[nl][og * 4 + 0] = x0.x; xl[nl][og * 4 + 1] = x0.y;
    xl[nl][og * 4 + 2] = x1.x; xl[nl][og * 4 + 3] = x1.y;
    __syncthreads();

#pragma unroll 4
    for (int b = 0; b < BB; ++b) {
        float xb0 = xl[nl][2 * b], xb1 = xl[nl][2 * b + 1];
        float yb0 = yl[nl][2 * b], yb1 = yl[nl][2 * b + 1];
        float4 o4;
        o4.x = xb0 * W[0].x + xb1 * W[1].x + yb0 * W[2].x + yb1 * W[3].x + W[4].x;
        o4.y = xb0 * W[0].y + xb1 * W[1].y + yb0 * W[2].y + yb1 * W[3].y + W[4].y;
        o4.z = xb0 * W[0].z + xb1 * W[1].z + yb0 * W[2].z + yb1 * W[3].z + W[4].z;
        o4.w = xb0 * W[0].w + xb1 * W[1].w + yb0 * W[2].w + yb1 * W[3].w + W[4].w;
        *(float4*)(out + ((size_t)b * NN + n) * HID + og * 4) = o4;
    }
}

// ---------------------------------------------------------------------------
extern "C" void kernel_launch(void* const* d_in, const int* in_sizes, int n_in,
                              void* d_out, int out_size, void* d_ws, size_t ws_size,
                              hipStream_t stream) {
    const float* x   = (const float*)d_in[0];   // [32, 8192, 2]
    const float* adj = (const float*)d_in[1];   // [8192, 16]
    const float* wp  = (const float*)d_in[2];   // [16, 2, 2, 64]
    const float* bp  = (const float*)d_in[3];   // [16, 64]
    float* out = (float*)d_out;                 // [32, 8192, 64]

    char* w = (char*)d_ws;
    short* VT   = (short*)w;                                     // 1 MB
    short* adjB = (short*)(w + (size_t)2 * 64 * VT_PITCH);       // 256 KB
    short* adjS = adjB + (size_t)NN * EMB;                       // 256 KB
    float* Wbuf = (float*)(w + (size_t)2 * 64 * VT_PITCH + (size_t)4 * NN * EMB);  // 10.5 MB
    float* ynum = Wbuf + (size_t)NN * 320;                       // MS*N*64 = 32 MB
    float* den  = ynum + (size_t)MS * NN * HID;                  // 512 KB

    k_build<<<640, 256, 0, stream>>>(x, adj, VT, adjB, adjS);
    k_weights<<<NN / 16, 256, 0, stream>>>(adj, wp, bp, Wbuf);
    k_prop<<<dim3(NN / TNB, MS), 256, 0, stream>>>(adjB, adjS, VT, ynum, den);
    k_epi<<<NN / 16, 256, 0, stream>>>(Wbuf, x, ynum, den, out);
}